// Round 2
// baseline (1047.469 us; speedup 1.0000x reference)
//
#include <hip/hip_runtime.h>
#include <cstdint>
#include <cstddef>

#define NE 16
#define TOPK 6
#define HID 1024
#define NTOK 8192
#define EPSF 1e-10f
#define CAP_ROWS 51200   // 400 mblocks * 128
#define MAXBLK 400

typedef short bf16x8 __attribute__((ext_vector_type(8)));
typedef float f32x4 __attribute__((ext_vector_type(4)));

__device__ __forceinline__ unsigned int f2bf_rne(float f) {
  union { float f; unsigned int u; } v;
  v.f = f;
  return (v.u + 0x7FFFu + ((v.u >> 16) & 1u)) >> 16;
}

__device__ __forceinline__ float bfbits2f(unsigned int hi16) {
  union { unsigned int u; float f; } v;
  v.u = hi16 << 16;
  return v.f;
}

__device__ __forceinline__ void load_lds16(const void* g, void* l) {
  __builtin_amdgcn_global_load_lds(
      (const __attribute__((address_space(1))) void*)g,
      (__attribute__((address_space(3))) void*)l, 16, 0, 0);
}

// ======================= SPARSE PATH =========================================

// router: logits -> softmax -> top6 -> per-assignment gates + histogram.
// Also fuses X fp32 -> bf16 conversion (row-major [t][k]).
// gate_k = q_k/s_top (the /(s+EPS) renorm and /acc cancel exactly);
// eps term = EPS * s/(s+EPS) with s = s_top/s_all, added in reduce epilogue.
__global__ __launch_bounds__(256) void router_sparse_kernel(
    const float* __restrict__ tokens, const float* __restrict__ rw,
    const float* __restrict__ rb, unsigned short* __restrict__ Xb,
    unsigned int* __restrict__ cnt, unsigned int* __restrict__ topk,
    float* __restrict__ g6, float* __restrict__ epst) {
  __shared__ float s_rw[NE * HID];
  const int tid = threadIdx.x;
  const int wv = tid >> 6;
  const int lane = tid & 63;
  const int token = blockIdx.x * 4 + wv;

  for (int i = tid; i < NE * HID / 4; i += 256)
    ((float4*)s_rw)[i] = ((const float4*)rw)[i];
  __syncthreads();

  const float* xp = tokens + (size_t)token * HID;
  float x[16];
#pragma unroll
  for (int j = 0; j < 16; ++j) x[j] = xp[lane + 64 * j];

  // fused bf16 convert of the token row (coalesced 128B stores)
  unsigned short* xbrow = Xb + (size_t)token * HID;
#pragma unroll
  for (int j = 0; j < 16; ++j)
    xbrow[lane + 64 * j] = (unsigned short)f2bf_rne(x[j]);

  float lg[NE];
#pragma unroll
  for (int e = 0; e < NE; ++e) {
    const float* w = s_rw + e * HID;
    float p = 0.f;
#pragma unroll
    for (int j = 0; j < 16; ++j) p += x[j] * w[lane + 64 * j];
    lg[e] = p;
  }
#pragma unroll
  for (int m = 1; m < 64; m <<= 1) {
#pragma unroll
    for (int e = 0; e < NE; ++e) lg[e] += __shfl_xor(lg[e], m);
  }
  if (lane == 0) {
    float mx = -1e30f;
#pragma unroll
    for (int e = 0; e < NE; ++e) {
      lg[e] += rb[e];
      mx = fmaxf(mx, lg[e]);
    }
    float q[NE];
    float s_all = 0.f;
#pragma unroll
    for (int e = 0; e < NE; ++e) {
      q[e] = expf(lg[e] - mx);
      s_all += q[e];
    }
    unsigned sel = 0, pack = 0;
    float s_top = 0.f;
    float gq[TOPK];
    int ge[TOPK];
#pragma unroll
    for (int k = 0; k < TOPK; ++k) {
      float best = -1.f;
      int bi = 0;
#pragma unroll
      for (int e = 0; e < NE; ++e) {
        bool taken = (sel >> e) & 1u;
        if (!taken && q[e] > best) { best = q[e]; bi = e; }
      }
      sel |= 1u << bi;
      gq[k] = best;
      ge[k] = bi;
      s_top += best;
      pack |= ((unsigned)bi) << (4 * k);
    }
#pragma unroll
    for (int k = 0; k < TOPK; ++k) {
      g6[(size_t)token * TOPK + k] = gq[k] / s_top;
      atomicAdd(&cnt[ge[k]], 1u);
    }
    topk[token] = pack;
    float s = s_top / s_all;
    epst[token] = EPSF * (s / (s + EPSF));
  }
}

// scan: 128-aligned per-expert segment offsets + mblock table. 1 block.
__global__ void scan_kernel(const unsigned int* __restrict__ cnt,
                            unsigned int* __restrict__ seg_off,
                            unsigned int* __restrict__ table,
                            unsigned int* __restrict__ total) {
  if (threadIdx.x == 0) {
    unsigned off = 0, b = 0;
    for (int e = 0; e < NE; ++e) {
      seg_off[e] = off;
      unsigned mb = (cnt[e] + 127) >> 7;
      for (unsigned m = 0; m < mb; ++m)
        table[b++] = ((unsigned)e << 24) | (off + m * 128);
      off += mb * 128;
    }
    *total = b;
  }
}

// assign: rank each (token,k) into its expert segment.
__global__ __launch_bounds__(256) void assign_kernel(
    const unsigned int* __restrict__ topk, const float* __restrict__ g6,
    const unsigned int* __restrict__ seg_off, unsigned int* __restrict__ fill,
    unsigned int* __restrict__ tokmap, float* __restrict__ gpos,
    unsigned int* __restrict__ inv) {
  const int t = blockIdx.x * 256 + threadIdx.x;
  const unsigned pack = topk[t];
#pragma unroll
  for (int k = 0; k < TOPK; ++k) {
    const unsigned e = (pack >> (4 * k)) & 15u;
    const unsigned pos = seg_off[e] + atomicAdd(&fill[e], 1u);
    tokmap[pos] = (unsigned)t;
    gpos[pos] = g6[(size_t)t * TOPK + k];
    inv[(size_t)t * TOPK + k] = pos;
  }
}

// W fp32 [e][k][n] -> bf16 transposed [e][n][k]
__global__ __launch_bounds__(256) void cvt_wt_kernel(
    const float* __restrict__ w, unsigned short* __restrict__ wt) {
  __shared__ float tile[64][65];
  const int kt = blockIdx.x * 64;
  const int nt = blockIdx.y * 64;
  const int e = blockIdx.z;
  const int tr = threadIdx.x >> 6;
  const int tc = threadIdx.x & 63;
  const float* wp = w + (size_t)e * HID * HID;
#pragma unroll
  for (int r = 0; r < 64; r += 4)
    tile[r + tr][tc] = wp[(size_t)(kt + r + tr) * HID + nt + tc];
  __syncthreads();
  unsigned short* wo = wt + (size_t)e * HID * HID;
#pragma unroll
  for (int c = 0; c < 64; c += 4)
    wo[(size_t)(nt + c + tr) * HID + kt + tc] =
        (unsigned short)f2bf_rne(tile[tc][c + tr]);
}

// grouped GEMM: Y[row, n] = gate[row] * (X[tok[row],:] @ We[:,n]), bf16 out.
// A rows gathered directly in global_load_lds staging (per-lane global addr).
__global__ __launch_bounds__(256, 3) void moe_ggemm_kernel(
    const unsigned short* __restrict__ Xb, const unsigned short* __restrict__ Wt,
    const unsigned int* __restrict__ table, const unsigned int* __restrict__ total,
    const unsigned int* __restrict__ tokmap, const float* __restrict__ gpos,
    unsigned short* __restrict__ Y) {
  __shared__ unsigned short As[128 * 32];
  __shared__ unsigned short Bs[128 * 32];
  __shared__ unsigned int Ts[128];
  __shared__ float Gs[128];

  const unsigned tot = *total;
  if (blockIdx.x >= tot) return;
  const unsigned ent = table[blockIdx.x];
  const int e = ent >> 24;
  const int row0 = ent & 0xFFFFFF;
  const int n0 = blockIdx.y * 128;

  const int tid = threadIdx.x;
  const int wv = tid >> 6;
  const int lane = tid & 63;
  const int lm = lane & 15;
  const int quad = lane >> 4;
  const int woff_m = (wv & 1) * 64;
  const int woff_n = (wv >> 1) * 64;

  if (tid < 128) {
    Ts[tid] = tokmap[row0 + tid];
    Gs[tid] = gpos[row0 + tid];
  }
  __syncthreads();

  const int srow = wv * 32 + (lane >> 2);
  const int schunk = (lane & 3) * 16;
  const char* gA0 = (const char*)Xb + (size_t)Ts[srow] * (HID * 2) + schunk;
  const char* gA1 = (const char*)Xb + (size_t)Ts[srow + 16] * (HID * 2) + schunk;
  const char* gB0 = (const char*)Wt + (size_t)e * (HID * HID * 2) +
                    (size_t)(n0 + srow) * (HID * 2) + schunk;
  const char* gB1 = gB0 + 16 * HID * 2;
  char* const lA0 = (char*)As + (wv * 32) * 64;
  char* const lA1 = lA0 + 16 * 64;
  char* const lB0 = (char*)Bs + (wv * 32) * 64;
  char* const lB1 = lB0 + 16 * 64;

  f32x4 acc[4][4];
#pragma unroll
  for (int i = 0; i < 4; ++i)
#pragma unroll
    for (int j = 0; j < 4; ++j) acc[i][j] = (f32x4){0.f, 0.f, 0.f, 0.f};

  for (int ks = 0; ks < 32; ++ks) {
    __syncthreads();
    load_lds16(gA0, lA0);
    load_lds16(gA1, lA1);
    load_lds16(gB0, lB0);
    load_lds16(gB1, lB1);
    gA0 += 64; gA1 += 64; gB0 += 64; gB1 += 64;
    __syncthreads();

    bf16x8 a[4], b[4];
#pragma unroll
    for (int i = 0; i < 4; ++i)
      a[i] = *(const bf16x8*)((const char*)As +
                              (woff_m + 16 * i + lm) * 64 + quad * 16);
#pragma unroll
    for (int j = 0; j < 4; ++j)
      b[j] = *(const bf16x8*)((const char*)Bs +
                              (woff_n + 16 * j + lm) * 64 + quad * 16);
#pragma unroll
    for (int i = 0; i < 4; ++i)
#pragma unroll
      for (int j = 0; j < 4; ++j)
        acc[i][j] =
            __builtin_amdgcn_mfma_f32_16x16x32_bf16(a[i], b[j], acc[i][j], 0, 0, 0);
  }

#pragma unroll
  for (int i = 0; i < 4; ++i)
#pragma unroll
    for (int r = 0; r < 4; ++r) {
      const int row = woff_m + 16 * i + quad * 4 + r;
      const float g = Gs[row];
      unsigned short* yrow = Y + (size_t)(row0 + row) * HID + n0;
#pragma unroll
      for (int j = 0; j < 4; ++j)
        yrow[woff_n + 16 * j + lm] = (unsigned short)f2bf_rne(g * acc[i][j][r]);
    }
}

// reduce: out[t,:] = sum_k Y[inv[t,k],:] + eps[t].  2 tokens/block.
__global__ __launch_bounds__(256) void reduce_kernel(
    const unsigned short* __restrict__ Y, const unsigned int* __restrict__ inv,
    const float* __restrict__ epst, float* __restrict__ out) {
  const int sub = threadIdx.x >> 7;
  const int ct = threadIdx.x & 127;
  const int t = blockIdx.x * 2 + sub;
  const int c0 = ct * 8;

  float s[8];
  const float ep = epst[t];
#pragma unroll
  for (int i = 0; i < 8; ++i) s[i] = ep;

#pragma unroll
  for (int k = 0; k < TOPK; ++k) {
    const unsigned pos = inv[(size_t)t * TOPK + k];
    const uint4 v = *(const uint4*)(Y + (size_t)pos * HID + c0);
    s[0] += bfbits2f(v.x & 0xFFFFu);
    s[1] += bfbits2f(v.x >> 16);
    s[2] += bfbits2f(v.y & 0xFFFFu);
    s[3] += bfbits2f(v.y >> 16);
    s[4] += bfbits2f(v.z & 0xFFFFu);
    s[5] += bfbits2f(v.z >> 16);
    s[6] += bfbits2f(v.w & 0xFFFFu);
    s[7] += bfbits2f(v.w >> 16);
  }
  float* orow = out + (size_t)t * HID + c0;
  *(float4*)orow = (float4){s[0], s[1], s[2], s[3]};
  *(float4*)(orow + 4) = (float4){s[4], s[5], s[6], s[7]};
}

// ======================= DENSE FALLBACK (round-1, passed) ====================

__global__ __launch_bounds__(256) void router_kernel(
    const float* __restrict__ tokens, const float* __restrict__ rw,
    const float* __restrict__ rb, float* __restrict__ gates,
    float* __restrict__ epst) {
  __shared__ float s_rw[NE * HID];
  const int tid = threadIdx.x;
  const int wv = tid >> 6;
  const int lane = tid & 63;
  const int token = blockIdx.x * 4 + wv;

  for (int i = tid; i < NE * HID / 4; i += 256)
    ((float4*)s_rw)[i] = ((const float4*)rw)[i];
  __syncthreads();

  const float* xp = tokens + (size_t)token * HID;
  float x[16];
#pragma unroll
  for (int j = 0; j < 16; ++j) x[j] = xp[lane + 64 * j];

  float lg[NE];
#pragma unroll
  for (int e = 0; e < NE; ++e) {
    const float* w = s_rw + e * HID;
    float p = 0.f;
#pragma unroll
    for (int j = 0; j < 16; ++j) p += x[j] * w[lane + 64 * j];
    lg[e] = p;
  }
#pragma unroll
  for (int m = 1; m < 64; m <<= 1) {
#pragma unroll
    for (int e = 0; e < NE; ++e) lg[e] += __shfl_xor(lg[e], m);
  }
  float mx = -1e30f;
#pragma unroll
  for (int e = 0; e < NE; ++e) {
    lg[e] += rb[e];
    mx = fmaxf(mx, lg[e]);
  }
  float q[NE];
  float s_all = 0.f;
#pragma unroll
  for (int e = 0; e < NE; ++e) {
    q[e] = expf(lg[e] - mx);
    s_all += q[e];
  }
  unsigned sel = 0;
  float s_top = 0.f;
  for (int k = 0; k < TOPK; ++k) {
    float best = -1.f;
    int bi = 0;
#pragma unroll
    for (int e = 0; e < NE; ++e) {
      bool taken = (sel >> e) & 1u;
      if (!taken && q[e] > best) { best = q[e]; bi = e; }
    }
    sel |= 1u << bi;
    s_top += best;
  }
  if (lane < NE) {
    float g = ((sel >> lane) & 1u) ? q[lane] / s_top : 0.f;
    gates[(size_t)token * NE + lane] = g;
  }
  if (lane == 32) {
    float s = s_top / s_all;
    epst[token] = EPSF * (s / (s + EPSF));
  }
}

__global__ __launch_bounds__(256) void cvt_x_kernel(
    const float* __restrict__ x, uint32_t* __restrict__ xb) {
  const size_t i = ((size_t)blockIdx.x * 256 + threadIdx.x) * 8;
  const float4 a = *(const float4*)(x + i);
  const float4 b = *(const float4*)(x + i + 4);
  uint4 o;
  o.x = f2bf_rne(a.x) | (f2bf_rne(a.y) << 16);
  o.y = f2bf_rne(a.z) | (f2bf_rne(a.w) << 16);
  o.z = f2bf_rne(b.x) | (f2bf_rne(b.y) << 16);
  o.w = f2bf_rne(b.z) | (f2bf_rne(b.w) << 16);
  *(uint4*)(xb + i / 2) = o;
}

__global__ __launch_bounds__(256, 2) void moe_gemm_kernel(
    const unsigned short* __restrict__ Xb, const unsigned short* __restrict__ Wt,
    const float* __restrict__ gates, const float* __restrict__ epst,
    float* __restrict__ out) {
  __shared__ unsigned short As[128 * 32];
  __shared__ unsigned short Bs[128 * 32];
  __shared__ float Gs[128 * NE];
  __shared__ float Es[128];

  const int tid = threadIdx.x;
  const int wv = tid >> 6;
  const int lane = tid & 63;
  const int t0 = blockIdx.x * 128;
  const int n0 = blockIdx.y * 128;
  const int lm = lane & 15;
  const int quad = lane >> 4;
  const int woff_m = (wv & 1) * 64;
  const int woff_n = (wv >> 1) * 64;

  {
    const float4* gsrc = (const float4*)(gates + (size_t)t0 * NE);
    float4* gdst = (float4*)Gs;
    gdst[tid] = gsrc[tid];
    gdst[tid + 256] = gsrc[tid + 256];
    if (tid < 128) Es[tid] = epst[t0 + tid];
  }

  const int srow = wv * 32 + (lane >> 2);
  const int schunk = (lane & 3) * 16;
  const char* gA0base = (const char*)Xb + (size_t)(t0 + srow) * (HID * 2) + schunk;
  const char* gA1base = gA0base + 16 * HID * 2;
  const char* gB0base0 = (const char*)Wt + (size_t)(n0 + srow) * (HID * 2) + schunk;
  const char* gB1base0 = gB0base0 + 16 * HID * 2;
  char* const lA0 = (char*)As + (wv * 32) * 64;
  char* const lA1 = lA0 + 16 * 64;
  char* const lB0 = (char*)Bs + (wv * 32) * 64;
  char* const lB1 = lB0 + 16 * 64;

  f32x4 fin[4][4];
#pragma unroll
  for (int i = 0; i < 4; ++i)
#pragma unroll
    for (int j = 0; j < 4; ++j) fin[i][j] = (f32x4){0.f, 0.f, 0.f, 0.f};

  for (int e = 0; e < NE; ++e) {
    f32x4 acc[4][4];
#pragma unroll
    for (int i = 0; i < 4; ++i)
#pragma unroll
      for (int j = 0; j < 4; ++j) acc[i][j] = (f32x4){0.f, 0.f, 0.f, 0.f};

    const char* gA0 = gA0base;
    const char* gA1 = gA1base;
    const char* gB0 = gB0base0 + (size_t)e * (HID * HID * 2);
    const char* gB1 = gB1base0 + (size_t)e * (HID * HID * 2);

    for (int ks = 0; ks < 32; ++ks) {
      __syncthreads();
      load_lds16(gA0, lA0);
      load_lds16(gA1, lA1);
      load_lds16(gB0, lB0);
      load_lds16(gB1, lB1);
      gA0 += 64; gA1 += 64; gB0 += 64; gB1 += 64;
      __syncthreads();

      bf16x8 a[4], b[4];
#pragma unroll
      for (int i = 0; i < 4; ++i)
        a[i] = *(const bf16x8*)((const char*)As +
                                (woff_m + 16 * i + lm) * 64 + quad * 16);
#pragma unroll
      for (int j = 0; j < 4; ++j)
        b[j] = *(const bf16x8*)((const char*)Bs +
                                (woff_n + 16 * j + lm) * 64 + quad * 16);
#pragma unroll
      for (int i = 0; i < 4; ++i)
#pragma unroll
        for (int j = 0; j < 4; ++j)
          acc[i][j] =
              __builtin_amdgcn_mfma_f32_16x16x32_bf16(a[i], b[j], acc[i][j], 0, 0, 0);
    }
#pragma unroll
    for (int i = 0; i < 4; ++i)
#pragma unroll
      for (int r = 0; r < 4; ++r) {
        const int row = woff_m + 16 * i + quad * 4 + r;
        const float g = Gs[row * NE + e];
#pragma unroll
        for (int j = 0; j < 4; ++j) fin[i][j][r] += g * acc[i][j][r];
      }
  }

#pragma unroll
  for (int i = 0; i < 4; ++i)
#pragma unroll
    for (int r = 0; r < 4; ++r) {
      const int row = woff_m + 16 * i + quad * 4 + r;
      const float ep = Es[row];
      float* orow = out + (size_t)(t0 + row) * HID + n0;
#pragma unroll
      for (int j = 0; j < 4; ++j)
        orow[woff_n + 16 * j + lm] = fin[i][j][r] + ep;
    }
}

// ======================= launch ==============================================

extern "C" void kernel_launch(void* const* d_in, const int* in_sizes, int n_in,
                              void* d_out, int out_size, void* d_ws, size_t ws_size,
                              hipStream_t stream) {
  const float* tokens = (const float*)d_in[0];  // [4,2048,1024] f32
  const float* rw = (const float*)d_in[1];      // [16,1024] f32
  const float* rb = (const float*)d_in[2];      // [16] f32
  const float* ew = (const float*)d_in[3];      // [16,1024,1024] f32
  float* out = (float*)d_out;                   // [4,2048,1024] f32

  char* ws = (char*)d_ws;

  // sparse-path workspace layout
  const size_t OFF_XB = 0;                        // 16 MB
  const size_t OFF_WT = 16777216;                 // 32 MB
  const size_t OFF_Y = 50331648;                  // 100 MB (51200 x 1024 bf16)
  const size_t OFF_META = 155189248;
  const size_t M_CNT = OFF_META + 0;              // 16 u32
  const size_t M_FILL = OFF_META + 64;            // 16 u32
  const size_t M_TOTAL = OFF_META + 128;          // 1 u32
  const size_t M_TOKMAP = OFF_META + 256;         // 51200 u32
  const size_t M_SEGOFF = OFF_META + 205056;      // 16 u32
  const size_t M_TABLE = OFF_META + 205120;       // 400 u32
  const size_t M_GPOS = OFF_META + 206720;        // 51200 f32
  const size_t M_INV = OFF_META + 411520;         // 49152 u32
  const size_t M_TOPK = OFF_META + 608128;        // 8192 u32
  const size_t M_G6 = OFF_META + 640896;          // 49152 f32
  const size_t M_EPST = OFF_META + 837504;        // 8192 f32
  const size_t NEED = OFF_META + 870272;          // ~148.9 MB

  if (ws_size >= NEED) {
    unsigned short* Xb = (unsigned short*)(ws + OFF_XB);
    unsigned short* Wt = (unsigned short*)(ws + OFF_WT);
    unsigned short* Y = (unsigned short*)(ws + OFF_Y);
    unsigned int* cnt = (unsigned int*)(ws + M_CNT);
    unsigned int* fill = (unsigned int*)(ws + M_FILL);
    unsigned int* total = (unsigned int*)(ws + M_TOTAL);
    unsigned int* tokmap = (unsigned int*)(ws + M_TOKMAP);
    unsigned int* seg_off = (unsigned int*)(ws + M_SEGOFF);
    unsigned int* table = (unsigned int*)(ws + M_TABLE);
    float* gpos = (float*)(ws + M_GPOS);
    unsigned int* inv = (unsigned int*)(ws + M_INV);
    unsigned int* topk = (unsigned int*)(ws + M_TOPK);
    float* g6 = (float*)(ws + M_G6);
    float* epst = (float*)(ws + M_EPST);

    // zero cnt/fill/total + tokmap (covers pad rows -> valid token 0)
    hipMemsetAsync(ws + OFF_META, 0, 256 + CAP_ROWS * 4, stream);

    router_sparse_kernel<<<dim3(NTOK / 4), dim3(256), 0, stream>>>(
        tokens, rw, rb, Xb, cnt, topk, g6, epst);
    cvt_wt_kernel<<<dim3(HID / 64, HID / 64, NE), dim3(256), 0, stream>>>(ew, Wt);
    scan_kernel<<<dim3(1), dim3(64), 0, stream>>>(cnt, seg_off, table, total);
    assign_kernel<<<dim3(NTOK / 256), dim3(256), 0, stream>>>(
        topk, g6, seg_off, fill, tokmap, gpos, inv);
    moe_ggemm_kernel<<<dim3(MAXBLK, HID / 128), dim3(256), 0, stream>>>(
        Xb, Wt, table, total, tokmap, gpos, Y);
    reduce_kernel<<<dim3(NTOK / 2), dim3(256), 0, stream>>>(Y, inv, epst, out);
  } else {
    // dense fallback (round-1 path, ~49 MB workspace)
    unsigned short* Xb = (unsigned short*)(ws);
    unsigned short* Wt = (unsigned short*)(ws + ((size_t)16 << 20));
    float* gates = (float*)(ws + ((size_t)48 << 20));
    float* epst = (float*)(ws + ((size_t)48 << 20) + (1 << 19));

    router_kernel<<<dim3(NTOK / 4), dim3(256), 0, stream>>>(tokens, rw, rb, gates, epst);
    cvt_x_kernel<<<dim3(NTOK * HID / (256 * 8)), dim3(256), 0, stream>>>(tokens, (uint32_t*)Xb);
    cvt_wt_kernel<<<dim3(HID / 64, HID / 64, NE), dim3(256), 0, stream>>>(ew, Wt);
    moe_gemm_kernel<<<dim3(NTOK / 128, HID / 128), dim3(256), 0, stream>>>(Xb, Wt, gates, epst, out);
  }
}

// Round 3
// 430.019 us; speedup vs baseline: 2.4359x; 2.4359x over previous
//
#include <hip/hip_runtime.h>
#include <cstdint>
#include <cstddef>

#define NE 16
#define TOPK 6
#define HID 1024
#define NTOK 8192
#define EPSF 1e-10f
#define CAP_ROWS 51200   // 400 mblocks * 128
#define MAXBLK 400

typedef short bf16x8 __attribute__((ext_vector_type(8)));
typedef float f32x4 __attribute__((ext_vector_type(4)));

__device__ __forceinline__ unsigned int f2bf_rne(float f) {
  union { float f; unsigned int u; } v;
  v.f = f;
  return (v.u + 0x7FFFu + ((v.u >> 16) & 1u)) >> 16;
}

__device__ __forceinline__ float bfbits2f(unsigned int hi16) {
  union { unsigned int u; float f; } v;
  v.u = hi16 << 16;
  return v.f;
}

__device__ __forceinline__ void load_lds16(const void* g, void* l) {
  __builtin_amdgcn_global_load_lds(
      (const __attribute__((address_space(1))) void*)g,
      (__attribute__((address_space(3))) void*)l, 16, 0, 0);
}

// ======================= SPARSE PATH =========================================

// router: logits -> softmax -> top6. NO global atomics (round-2's 49k atomics
// onto one cache line serialized at the TCC -> 597us). All lanes redundantly
// compute the top-k; lanes 0..5 write g6, lane 0 writes pack+eps.
// gate_k = q_k/s_top (the /(s+EPS) renorm and /acc cancel exactly);
// eps term = EPS * s/(s+EPS) with s = s_top/s_all, added in reduce epilogue.
__global__ __launch_bounds__(256) void router_sparse_kernel(
    const float* __restrict__ tokens, const float* __restrict__ rw,
    const float* __restrict__ rb, unsigned short* __restrict__ Xb,
    unsigned int* __restrict__ topk, float* __restrict__ g6,
    float* __restrict__ epst) {
  __shared__ float s_rw[NE * HID];
  const int tid = threadIdx.x;
  const int wv = tid >> 6;
  const int lane = tid & 63;
  const int token = blockIdx.x * 4 + wv;

  for (int i = tid; i < NE * HID / 4; i += 256)
    ((float4*)s_rw)[i] = ((const float4*)rw)[i];
  __syncthreads();

  const float* xp = tokens + (size_t)token * HID;
  float x[16];
#pragma unroll
  for (int j = 0; j < 16; ++j) x[j] = xp[lane + 64 * j];

  // fused bf16 convert of the token row
  unsigned short* xbrow = Xb + (size_t)token * HID;
#pragma unroll
  for (int j = 0; j < 16; ++j)
    xbrow[lane + 64 * j] = (unsigned short)f2bf_rne(x[j]);

  float lg[NE];
#pragma unroll
  for (int e = 0; e < NE; ++e) {
    const float* w = s_rw + e * HID;
    float p = 0.f;
#pragma unroll
    for (int j = 0; j < 16; ++j) p += x[j] * w[lane + 64 * j];
    lg[e] = p;
  }
#pragma unroll
  for (int m = 1; m < 64; m <<= 1) {
#pragma unroll
    for (int e = 0; e < NE; ++e) lg[e] += __shfl_xor(lg[e], m);
  }
  // all lanes now hold identical logits; redundant epilogue, parallel writes
  float mx = -1e30f;
#pragma unroll
  for (int e = 0; e < NE; ++e) {
    lg[e] += rb[e];
    mx = fmaxf(mx, lg[e]);
  }
  float q[NE];
  float s_all = 0.f;
#pragma unroll
  for (int e = 0; e < NE; ++e) {
    q[e] = expf(lg[e] - mx);
    s_all += q[e];
  }
  unsigned sel = 0, pack = 0;
  float s_top = 0.f;
  float gq[TOPK];
#pragma unroll
  for (int k = 0; k < TOPK; ++k) {
    float best = -1.f;
    int bi = 0;
#pragma unroll
    for (int e = 0; e < NE; ++e) {
      bool taken = (sel >> e) & 1u;
      if (!taken && q[e] > best) { best = q[e]; bi = e; }
    }
    sel |= 1u << bi;
    gq[k] = best;
    s_top += best;
    pack |= ((unsigned)bi) << (4 * k);
  }
  if (lane < TOPK)
    g6[(size_t)token * TOPK + lane] = gq[lane] / s_top;
  if (lane == 32) {
    topk[token] = pack;
    float s = s_top / s_all;
    epst[token] = EPSF * (s / (s + EPSF));
  }
}

// histogram (LDS atomics, 1 block) + 128-aligned segment offsets + mblock table
__global__ __launch_bounds__(256) void hist_scan_kernel(
    const unsigned int* __restrict__ topk, unsigned int* __restrict__ seg_off,
    unsigned int* __restrict__ table, unsigned int* __restrict__ total) {
  __shared__ unsigned int h[NE];
  if (threadIdx.x < NE) h[threadIdx.x] = 0;
  __syncthreads();
  for (int t = threadIdx.x; t < NTOK; t += 256) {
    const unsigned p = topk[t];
#pragma unroll
    for (int k = 0; k < TOPK; ++k) atomicAdd(&h[(p >> (4 * k)) & 15u], 1u);
  }
  __syncthreads();
  if (threadIdx.x == 0) {
    unsigned off = 0, b = 0;
    for (int e = 0; e < NE; ++e) {
      seg_off[e] = off;
      unsigned mb = (h[e] + 127) >> 7;
      for (unsigned m = 0; m < mb; ++m)
        table[b++] = ((unsigned)e << 24) | (off + m * 128);
      off += mb * 128;
    }
    *total = b;
  }
}

// assign: one block per expert; deterministic rank via block prefix-sum.
// No global atomics. Thread t scans tokens [t*32, t*32+32).
__global__ __launch_bounds__(256) void assign_kernel(
    const unsigned int* __restrict__ topk, const float* __restrict__ g6,
    const unsigned int* __restrict__ seg_off,
    unsigned int* __restrict__ tokmap, float* __restrict__ gpos,
    unsigned int* __restrict__ inv) {
  __shared__ unsigned int s_sc[256];
  const int e = blockIdx.x;
  const int tid = threadIdx.x;
  const int tbase = tid * (NTOK / 256);

  unsigned c = 0;
  for (int i = 0; i < NTOK / 256; ++i) {
    const unsigned p = topk[tbase + i];
#pragma unroll
    for (int k = 0; k < TOPK; ++k) c += (((p >> (4 * k)) & 15u) == (unsigned)e);
  }
  s_sc[tid] = c;
  __syncthreads();
  // inclusive Hillis-Steele scan over 256 counts
  for (int off = 1; off < 256; off <<= 1) {
    unsigned v = (tid >= off) ? s_sc[tid - off] : 0u;
    __syncthreads();
    s_sc[tid] += v;
    __syncthreads();
  }
  unsigned pos = seg_off[e] + s_sc[tid] - c;
  for (int i = 0; i < NTOK / 256; ++i) {
    const int t = tbase + i;
    const unsigned p = topk[t];
#pragma unroll
    for (int k = 0; k < TOPK; ++k) {
      if (((p >> (4 * k)) & 15u) == (unsigned)e) {
        tokmap[pos] = (unsigned)t;
        gpos[pos] = g6[(size_t)t * TOPK + k];
        inv[(size_t)t * TOPK + k] = pos;
        ++pos;
      }
    }
  }
}

// W fp32 [e][k][n] -> bf16 transposed [e][n][k]
__global__ __launch_bounds__(256) void cvt_wt_kernel(
    const float* __restrict__ w, unsigned short* __restrict__ wt) {
  __shared__ float tile[64][65];
  const int kt = blockIdx.x * 64;
  const int nt = blockIdx.y * 64;
  const int e = blockIdx.z;
  const int tr = threadIdx.x >> 6;
  const int tc = threadIdx.x & 63;
  const float* wp = w + (size_t)e * HID * HID;
#pragma unroll
  for (int r = 0; r < 64; r += 4)
    tile[r + tr][tc] = wp[(size_t)(kt + r + tr) * HID + nt + tc];
  __syncthreads();
  unsigned short* wo = wt + (size_t)e * HID * HID;
#pragma unroll
  for (int c = 0; c < 64; c += 4)
    wo[(size_t)(nt + c + tr) * HID + kt + tc] =
        (unsigned short)f2bf_rne(tile[tc][c + tr]);
}

// grouped GEMM: Y[row, n] = gate[row] * (X[tok[row],:] @ We[:,n]), bf16 out.
__global__ __launch_bounds__(256, 3) void moe_ggemm_kernel(
    const unsigned short* __restrict__ Xb, const unsigned short* __restrict__ Wt,
    const unsigned int* __restrict__ table, const unsigned int* __restrict__ total,
    const unsigned int* __restrict__ tokmap, const float* __restrict__ gpos,
    unsigned short* __restrict__ Y) {
  __shared__ unsigned short As[128 * 32];
  __shared__ unsigned short Bs[128 * 32];
  __shared__ unsigned int Ts[128];
  __shared__ float Gs[128];

  const unsigned tot = *total;
  if (blockIdx.x >= tot) return;
  const unsigned ent = table[blockIdx.x];
  const int e = ent >> 24;
  const int row0 = ent & 0xFFFFFF;
  const int n0 = blockIdx.y * 128;

  const int tid = threadIdx.x;
  const int wv = tid >> 6;
  const int lane = tid & 63;
  const int lm = lane & 15;
  const int quad = lane >> 4;
  const int woff_m = (wv & 1) * 64;
  const int woff_n = (wv >> 1) * 64;

  if (tid < 128) {
    Ts[tid] = tokmap[row0 + tid];
    Gs[tid] = gpos[row0 + tid];
  }
  __syncthreads();

  const int srow = wv * 32 + (lane >> 2);
  const int schunk = (lane & 3) * 16;
  const char* gA0 = (const char*)Xb + (size_t)Ts[srow] * (HID * 2) + schunk;
  const char* gA1 = (const char*)Xb + (size_t)Ts[srow + 16] * (HID * 2) + schunk;
  const char* gB0 = (const char*)Wt + (size_t)e * (HID * HID * 2) +
                    (size_t)(n0 + srow) * (HID * 2) + schunk;
  const char* gB1 = gB0 + 16 * HID * 2;
  char* const lA0 = (char*)As + (wv * 32) * 64;
  char* const lA1 = lA0 + 16 * 64;
  char* const lB0 = (char*)Bs + (wv * 32) * 64;
  char* const lB1 = lB0 + 16 * 64;

  f32x4 acc[4][4];
#pragma unroll
  for (int i = 0; i < 4; ++i)
#pragma unroll
    for (int j = 0; j < 4; ++j) acc[i][j] = (f32x4){0.f, 0.f, 0.f, 0.f};

  for (int ks = 0; ks < 32; ++ks) {
    __syncthreads();
    load_lds16(gA0, lA0);
    load_lds16(gA1, lA1);
    load_lds16(gB0, lB0);
    load_lds16(gB1, lB1);
    gA0 += 64; gA1 += 64; gB0 += 64; gB1 += 64;
    __syncthreads();

    bf16x8 a[4], b[4];
#pragma unroll
    for (int i = 0; i < 4; ++i)
      a[i] = *(const bf16x8*)((const char*)As +
                              (woff_m + 16 * i + lm) * 64 + quad * 16);
#pragma unroll
    for (int j = 0; j < 4; ++j)
      b[j] = *(const bf16x8*)((const char*)Bs +
                              (woff_n + 16 * j + lm) * 64 + quad * 16);
#pragma unroll
    for (int i = 0; i < 4; ++i)
#pragma unroll
      for (int j = 0; j < 4; ++j)
        acc[i][j] =
            __builtin_amdgcn_mfma_f32_16x16x32_bf16(a[i], b[j], acc[i][j], 0, 0, 0);
  }

#pragma unroll
  for (int i = 0; i < 4; ++i)
#pragma unroll
    for (int r = 0; r < 4; ++r) {
      const int row = woff_m + 16 * i + quad * 4 + r;
      const float g = Gs[row];
      unsigned short* yrow = Y + (size_t)(row0 + row) * HID + n0;
#pragma unroll
      for (int j = 0; j < 4; ++j)
        yrow[woff_n + 16 * j + lm] = (unsigned short)f2bf_rne(g * acc[i][j][r]);
    }
}

// reduce: out[t,:] = sum_k Y[inv[t,k],:] + eps[t].  2 tokens/block.
__global__ __launch_bounds__(256) void reduce_kernel(
    const unsigned short* __restrict__ Y, const unsigned int* __restrict__ inv,
    const float* __restrict__ epst, float* __restrict__ out) {
  const int sub = threadIdx.x >> 7;
  const int ct = threadIdx.x & 127;
  const int t = blockIdx.x * 2 + sub;
  const int c0 = ct * 8;

  float s[8];
  const float ep = epst[t];
#pragma unroll
  for (int i = 0; i < 8; ++i) s[i] = ep;

#pragma unroll
  for (int k = 0; k < TOPK; ++k) {
    const unsigned pos = inv[(size_t)t * TOPK + k];
    const uint4 v = *(const uint4*)(Y + (size_t)pos * HID + c0);
    s[0] += bfbits2f(v.x & 0xFFFFu);
    s[1] += bfbits2f(v.x >> 16);
    s[2] += bfbits2f(v.y & 0xFFFFu);
    s[3] += bfbits2f(v.y >> 16);
    s[4] += bfbits2f(v.z & 0xFFFFu);
    s[5] += bfbits2f(v.z >> 16);
    s[6] += bfbits2f(v.w & 0xFFFFu);
    s[7] += bfbits2f(v.w >> 16);
  }
  float* orow = out + (size_t)t * HID + c0;
  *(float4*)orow = (float4){s[0], s[1], s[2], s[3]};
  *(float4*)(orow + 4) = (float4){s[4], s[5], s[6], s[7]};
}

// ======================= DENSE FALLBACK (round-1, passed) ====================

__global__ __launch_bounds__(256) void router_kernel(
    const float* __restrict__ tokens, const float* __restrict__ rw,
    const float* __restrict__ rb, float* __restrict__ gates,
    float* __restrict__ epst) {
  __shared__ float s_rw[NE * HID];
  const int tid = threadIdx.x;
  const int wv = tid >> 6;
  const int lane = tid & 63;
  const int token = blockIdx.x * 4 + wv;

  for (int i = tid; i < NE * HID / 4; i += 256)
    ((float4*)s_rw)[i] = ((const float4*)rw)[i];
  __syncthreads();

  const float* xp = tokens + (size_t)token * HID;
  float x[16];
#pragma unroll
  for (int j = 0; j < 16; ++j) x[j] = xp[lane + 64 * j];

  float lg[NE];
#pragma unroll
  for (int e = 0; e < NE; ++e) {
    const float* w = s_rw + e * HID;
    float p = 0.f;
#pragma unroll
    for (int j = 0; j < 16; ++j) p += x[j] * w[lane + 64 * j];
    lg[e] = p;
  }
#pragma unroll
  for (int m = 1; m < 64; m <<= 1) {
#pragma unroll
    for (int e = 0; e < NE; ++e) lg[e] += __shfl_xor(lg[e], m);
  }
  float mx = -1e30f;
#pragma unroll
  for (int e = 0; e < NE; ++e) {
    lg[e] += rb[e];
    mx = fmaxf(mx, lg[e]);
  }
  float q[NE];
  float s_all = 0.f;
#pragma unroll
  for (int e = 0; e < NE; ++e) {
    q[e] = expf(lg[e] - mx);
    s_all += q[e];
  }
  unsigned sel = 0;
  float s_top = 0.f;
  for (int k = 0; k < TOPK; ++k) {
    float best = -1.f;
    int bi = 0;
#pragma unroll
    for (int e = 0; e < NE; ++e) {
      bool taken = (sel >> e) & 1u;
      if (!taken && q[e] > best) { best = q[e]; bi = e; }
    }
    sel |= 1u << bi;
    s_top += best;
  }
  if (lane < NE) {
    float g = ((sel >> lane) & 1u) ? q[lane] / s_top : 0.f;
    gates[(size_t)token * NE + lane] = g;
  }
  if (lane == 32) {
    float s = s_top / s_all;
    epst[token] = EPSF * (s / (s + EPSF));
  }
}

__global__ __launch_bounds__(256) void cvt_x_kernel(
    const float* __restrict__ x, uint32_t* __restrict__ xb) {
  const size_t i = ((size_t)blockIdx.x * 256 + threadIdx.x) * 8;
  const float4 a = *(const float4*)(x + i);
  const float4 b = *(const float4*)(x + i + 4);
  uint4 o;
  o.x = f2bf_rne(a.x) | (f2bf_rne(a.y) << 16);
  o.y = f2bf_rne(a.z) | (f2bf_rne(a.w) << 16);
  o.z = f2bf_rne(b.x) | (f2bf_rne(b.y) << 16);
  o.w = f2bf_rne(b.z) | (f2bf_rne(b.w) << 16);
  *(uint4*)(xb + i / 2) = o;
}

__global__ __launch_bounds__(256, 2) void moe_gemm_kernel(
    const unsigned short* __restrict__ Xb, const unsigned short* __restrict__ Wt,
    const float* __restrict__ gates, const float* __restrict__ epst,
    float* __restrict__ out) {
  __shared__ unsigned short As[128 * 32];
  __shared__ unsigned short Bs[128 * 32];
  __shared__ float Gs[128 * NE];
  __shared__ float Es[128];

  const int tid = threadIdx.x;
  const int wv = tid >> 6;
  const int lane = tid & 63;
  const int t0 = blockIdx.x * 128;
  const int n0 = blockIdx.y * 128;
  const int lm = lane & 15;
  const int quad = lane >> 4;
  const int woff_m = (wv & 1) * 64;
  const int woff_n = (wv >> 1) * 64;

  {
    const float4* gsrc = (const float4*)(gates + (size_t)t0 * NE);
    float4* gdst = (float4*)Gs;
    gdst[tid] = gsrc[tid];
    gdst[tid + 256] = gsrc[tid + 256];
    if (tid < 128) Es[tid] = epst[t0 + tid];
  }

  const int srow = wv * 32 + (lane >> 2);
  const int schunk = (lane & 3) * 16;
  const char* gA0base = (const char*)Xb + (size_t)(t0 + srow) * (HID * 2) + schunk;
  const char* gA1base = gA0base + 16 * HID * 2;
  const char* gB0base0 = (const char*)Wt + (size_t)(n0 + srow) * (HID * 2) + schunk;
  const char* gB1base0 = gB0base0 + 16 * HID * 2;
  char* const lA0 = (char*)As + (wv * 32) * 64;
  char* const lA1 = lA0 + 16 * 64;
  char* const lB0 = (char*)Bs + (wv * 32) * 64;
  char* const lB1 = lB0 + 16 * 64;

  f32x4 fin[4][4];
#pragma unroll
  for (int i = 0; i < 4; ++i)
#pragma unroll
    for (int j = 0; j < 4; ++j) fin[i][j] = (f32x4){0.f, 0.f, 0.f, 0.f};

  for (int e = 0; e < NE; ++e) {
    f32x4 acc[4][4];
#pragma unroll
    for (int i = 0; i < 4; ++i)
#pragma unroll
      for (int j = 0; j < 4; ++j) acc[i][j] = (f32x4){0.f, 0.f, 0.f, 0.f};

    const char* gA0 = gA0base;
    const char* gA1 = gA1base;
    const char* gB0 = gB0base0 + (size_t)e * (HID * HID * 2);
    const char* gB1 = gB1base0 + (size_t)e * (HID * HID * 2);

    for (int ks = 0; ks < 32; ++ks) {
      __syncthreads();
      load_lds16(gA0, lA0);
      load_lds16(gA1, lA1);
      load_lds16(gB0, lB0);
      load_lds16(gB1, lB1);
      gA0 += 64; gA1 += 64; gB0 += 64; gB1 += 64;
      __syncthreads();

      bf16x8 a[4], b[4];
#pragma unroll
      for (int i = 0; i < 4; ++i)
        a[i] = *(const bf16x8*)((const char*)As +
                                (woff_m + 16 * i + lm) * 64 + quad * 16);
#pragma unroll
      for (int j = 0; j < 4; ++j)
        b[j] = *(const bf16x8*)((const char*)Bs +
                                (woff_n + 16 * j + lm) * 64 + quad * 16);
#pragma unroll
      for (int i = 0; i < 4; ++i)
#pragma unroll
        for (int j = 0; j < 4; ++j)
          acc[i][j] =
              __builtin_amdgcn_mfma_f32_16x16x32_bf16(a[i], b[j], acc[i][j], 0, 0, 0);
    }
#pragma unroll
    for (int i = 0; i < 4; ++i)
#pragma unroll
      for (int r = 0; r < 4; ++r) {
        const int row = woff_m + 16 * i + quad * 4 + r;
        const float g = Gs[row * NE + e];
#pragma unroll
        for (int j = 0; j < 4; ++j) fin[i][j][r] += g * acc[i][j][r];
      }
  }

#pragma unroll
  for (int i = 0; i < 4; ++i)
#pragma unroll
    for (int r = 0; r < 4; ++r) {
      const int row = woff_m + 16 * i + quad * 4 + r;
      const float ep = Es[row];
      float* orow = out + (size_t)(t0 + row) * HID + n0;
#pragma unroll
      for (int j = 0; j < 4; ++j)
        orow[woff_n + 16 * j + lm] = fin[i][j][r] + ep;
    }
}

// ======================= launch ==============================================

extern "C" void kernel_launch(void* const* d_in, const int* in_sizes, int n_in,
                              void* d_out, int out_size, void* d_ws, size_t ws_size,
                              hipStream_t stream) {
  const float* tokens = (const float*)d_in[0];  // [4,2048,1024] f32
  const float* rw = (const float*)d_in[1];      // [16,1024] f32
  const float* rb = (const float*)d_in[2];      // [16] f32
  const float* ew = (const float*)d_in[3];      // [16,1024,1024] f32
  float* out = (float*)d_out;                   // [4,2048,1024] f32

  char* ws = (char*)d_ws;

  // sparse-path workspace layout
  const size_t OFF_XB = 0;                        // 16 MB
  const size_t OFF_WT = 16777216;                 // 32 MB
  const size_t OFF_Y = 50331648;                  // 100 MB (51200 x 1024 bf16)
  const size_t OFF_META = 155189248;
  const size_t M_TOKMAP = OFF_META + 0;           // 51200 u32
  const size_t M_GPOS = OFF_META + 204800;        // 51200 f32
  const size_t M_TOTAL = OFF_META + 409600;       // 1 u32 (pad 64)
  const size_t M_SEGOFF = OFF_META + 409664;      // 16 u32
  const size_t M_TABLE = OFF_META + 409728;       // 400 u32 (pad)
  const size_t M_INV = OFF_META + 411392;         // 49152 u32
  const size_t M_TOPK = OFF_META + 608000;        // 8192 u32
  const size_t M_G6 = OFF_META + 640768;          // 49152 f32
  const size_t M_EPST = OFF_META + 837376;        // 8192 f32
  const size_t NEED = OFF_META + 870144;          // ~148.9 MB

  if (ws_size >= NEED) {
    unsigned short* Xb = (unsigned short*)(ws + OFF_XB);
    unsigned short* Wt = (unsigned short*)(ws + OFF_WT);
    unsigned short* Y = (unsigned short*)(ws + OFF_Y);
    unsigned int* tokmap = (unsigned int*)(ws + M_TOKMAP);
    float* gpos = (float*)(ws + M_GPOS);
    unsigned int* total = (unsigned int*)(ws + M_TOTAL);
    unsigned int* seg_off = (unsigned int*)(ws + M_SEGOFF);
    unsigned int* table = (unsigned int*)(ws + M_TABLE);
    unsigned int* inv = (unsigned int*)(ws + M_INV);
    unsigned int* topk = (unsigned int*)(ws + M_TOPK);
    float* g6 = (float*)(ws + M_G6);
    float* epst = (float*)(ws + M_EPST);

    // zero tokmap+gpos (pad rows -> valid token 0, gate 0)
    hipMemsetAsync(ws + M_TOKMAP, 0, 409600, stream);

    router_sparse_kernel<<<dim3(NTOK / 4), dim3(256), 0, stream>>>(
        tokens, rw, rb, Xb, topk, g6, epst);
    cvt_wt_kernel<<<dim3(HID / 64, HID / 64, NE), dim3(256), 0, stream>>>(ew, Wt);
    hist_scan_kernel<<<dim3(1), dim3(256), 0, stream>>>(topk, seg_off, table, total);
    assign_kernel<<<dim3(NE), dim3(256), 0, stream>>>(
        topk, g6, seg_off, tokmap, gpos, inv);
    moe_ggemm_kernel<<<dim3(MAXBLK, HID / 128), dim3(256), 0, stream>>>(
        Xb, Wt, table, total, tokmap, gpos, Y);
    reduce_kernel<<<dim3(NTOK / 2), dim3(256), 0, stream>>>(Y, inv, epst, out);
  } else {
    // dense fallback (round-1 path, ~49 MB workspace)
    unsigned short* Xb = (unsigned short*)(ws);
    unsigned short* Wt = (unsigned short*)(ws + ((size_t)16 << 20));
    float* gates = (float*)(ws + ((size_t)48 << 20));
    float* epst = (float*)(ws + ((size_t)48 << 20) + (1 << 19));

    router_kernel<<<dim3(NTOK / 4), dim3(256), 0, stream>>>(tokens, rw, rb, gates, epst);
    cvt_x_kernel<<<dim3(NTOK * HID / (256 * 8)), dim3(256), 0, stream>>>(tokens, (uint32_t*)Xb);
    cvt_wt_kernel<<<dim3(HID / 64, HID / 64, NE), dim3(256), 0, stream>>>(ew, Wt);
    moe_gemm_kernel<<<dim3(NTOK / 128, HID / 128), dim3(256), 0, stream>>>(Xb, Wt, gates, epst, out);
  }
}

// Round 4
// 398.955 us; speedup vs baseline: 2.6255x; 1.0779x over previous
//
#include <hip/hip_runtime.h>
#include <cstdint>
#include <cstddef>

#define NE 16
#define TOPK 6
#define HID 1024
#define NTOK 8192
#define EPSF 1e-10f
#define CAP_ROWS 51200   // 400 mblocks * 128
#define MAXBLK 400

typedef short bf16x8 __attribute__((ext_vector_type(8)));
typedef float f32x4 __attribute__((ext_vector_type(4)));

__device__ __forceinline__ unsigned int f2bf_rne(float f) {
  union { float f; unsigned int u; } v;
  v.f = f;
  return (v.u + 0x7FFFu + ((v.u >> 16) & 1u)) >> 16;
}

__device__ __forceinline__ float bfbits2f(unsigned int hi16) {
  union { unsigned int u; float f; } v;
  v.u = hi16 << 16;
  return v.f;
}

__device__ __forceinline__ void load_lds16(const void* g, void* l) {
  __builtin_amdgcn_global_load_lds(
      (const __attribute__((address_space(1))) void*)g,
      (__attribute__((address_space(3))) void*)l, 16, 0, 0);
}

// router: logits -> softmax -> top6. No global atomics (round-2 lesson: 49k
// same-line TCC atomics serialized -> 597us). All lanes redundantly compute
// top-k; lanes 0..5 write g6, lane 32 writes pack+eps. Fuses X f32->bf16.
// gate_k = q_k/s_top (renorm and /acc cancel); eps = EPS*s/(s+EPS).
__global__ __launch_bounds__(256) void router_sparse_kernel(
    const float* __restrict__ tokens, const float* __restrict__ rw,
    const float* __restrict__ rb, unsigned short* __restrict__ Xb,
    unsigned int* __restrict__ topk, float* __restrict__ g6,
    float* __restrict__ epst) {
  __shared__ float s_rw[NE * HID];
  const int tid = threadIdx.x;
  const int wv = tid >> 6;
  const int lane = tid & 63;
  const int token = blockIdx.x * 4 + wv;

  for (int i = tid; i < NE * HID / 4; i += 256)
    ((float4*)s_rw)[i] = ((const float4*)rw)[i];
  __syncthreads();

  const float* xp = tokens + (size_t)token * HID;
  float x[16];
#pragma unroll
  for (int j = 0; j < 16; ++j) x[j] = xp[lane + 64 * j];

  unsigned short* xbrow = Xb + (size_t)token * HID;
#pragma unroll
  for (int j = 0; j < 16; ++j)
    xbrow[lane + 64 * j] = (unsigned short)f2bf_rne(x[j]);

  float lg[NE];
#pragma unroll
  for (int e = 0; e < NE; ++e) {
    const float* w = s_rw + e * HID;
    float p = 0.f;
#pragma unroll
    for (int j = 0; j < 16; ++j) p += x[j] * w[lane + 64 * j];
    lg[e] = p;
  }
#pragma unroll
  for (int m = 1; m < 64; m <<= 1) {
#pragma unroll
    for (int e = 0; e < NE; ++e) lg[e] += __shfl_xor(lg[e], m);
  }
  float mx = -1e30f;
#pragma unroll
  for (int e = 0; e < NE; ++e) {
    lg[e] += rb[e];
    mx = fmaxf(mx, lg[e]);
  }
  float q[NE];
  float s_all = 0.f;
#pragma unroll
  for (int e = 0; e < NE; ++e) {
    q[e] = expf(lg[e] - mx);
    s_all += q[e];
  }
  unsigned sel = 0, pack = 0;
  float s_top = 0.f;
  float gq[TOPK];
#pragma unroll
  for (int k = 0; k < TOPK; ++k) {
    float best = -1.f;
    int bi = 0;
#pragma unroll
    for (int e = 0; e < NE; ++e) {
      bool taken = (sel >> e) & 1u;
      if (!taken && q[e] > best) { best = q[e]; bi = e; }
    }
    sel |= 1u << bi;
    gq[k] = best;
    s_top += best;
    pack |= ((unsigned)bi) << (4 * k);
  }
  if (lane < TOPK)
    g6[(size_t)token * TOPK + lane] = gq[lane] / s_top;
  if (lane == 32) {
    topk[token] = pack;
    float s = s_top / s_all;
    epst[token] = EPSF * (s / (s + EPSF));
  }
}

// merged hist + scan + rank-scatter + pad-fill. One block per expert.
// Each block redundantly histograms all experts (LDS atomics), derives
// 128-aligned segment offsets locally; block 0 also writes mblock table+total.
// Deterministic rank via Hillis-Steele prefix scan; no global atomics.
__global__ __launch_bounds__(256) void sortassign_kernel(
    const unsigned int* __restrict__ topk, const float* __restrict__ g6,
    unsigned int* __restrict__ tokmap, float* __restrict__ gpos,
    unsigned int* __restrict__ inv, unsigned int* __restrict__ table,
    unsigned int* __restrict__ total) {
  __shared__ unsigned int hist[NE];
  __shared__ unsigned int s_seg[NE];
  __shared__ unsigned int s_sc[256];
  const int e = blockIdx.x;
  const int tid = threadIdx.x;

  if (tid < NE) hist[tid] = 0;
  __syncthreads();
  for (int t = tid; t < NTOK; t += 256) {
    const unsigned p = topk[t];
#pragma unroll
    for (int k = 0; k < TOPK; ++k) atomicAdd(&hist[(p >> (4 * k)) & 15u], 1u);
  }
  __syncthreads();
  if (tid == 0) {
    unsigned off = 0;
    for (int i = 0; i < NE; ++i) {
      s_seg[i] = off;
      off += ((hist[i] + 127) >> 7) << 7;
    }
  }
  __syncthreads();
  if (e == 0 && tid == 0) {
    unsigned b = 0;
    for (int i = 0; i < NE; ++i) {
      unsigned mb = (hist[i] + 127) >> 7;
      for (unsigned m = 0; m < mb; ++m)
        table[b++] = ((unsigned)i << 24) | (s_seg[i] + m * 128);
    }
    *total = b;
  }

  const int tbase = tid * (NTOK / 256);
  unsigned c = 0;
  for (int i = 0; i < NTOK / 256; ++i) {
    const unsigned p = topk[tbase + i];
#pragma unroll
    for (int k = 0; k < TOPK; ++k) c += (((p >> (4 * k)) & 15u) == (unsigned)e);
  }
  s_sc[tid] = c;
  __syncthreads();
  for (int off = 1; off < 256; off <<= 1) {
    unsigned v = (tid >= off) ? s_sc[tid - off] : 0u;
    __syncthreads();
    s_sc[tid] += v;
    __syncthreads();
  }
  const unsigned seg0 = s_seg[e];
  unsigned pos = seg0 + s_sc[tid] - c;
  for (int i = 0; i < NTOK / 256; ++i) {
    const int t = tbase + i;
    const unsigned p = topk[t];
#pragma unroll
    for (int k = 0; k < TOPK; ++k) {
      if (((p >> (4 * k)) & 15u) == (unsigned)e) {
        tokmap[pos] = (unsigned)t;
        gpos[pos] = g6[(size_t)t * TOPK + k];
        inv[(size_t)t * TOPK + k] = pos;
        ++pos;
      }
    }
  }
  // zero-fill pad tail of this expert's segment (replaces the memset)
  const unsigned cnt_e = s_sc[255];
  const unsigned segend = seg0 + (((cnt_e + 127) >> 7) << 7);
  for (unsigned p2 = seg0 + cnt_e + tid; p2 < segend; p2 += 256) {
    tokmap[p2] = 0u;
    gpos[p2] = 0.f;
  }
}

// W fp32 [e][k][n] -> bf16 transposed [e][n][k]; vectorized u32 stores.
__global__ __launch_bounds__(256) void cvt_wt_kernel(
    const float* __restrict__ w, unsigned short* __restrict__ wt) {
  __shared__ float tile[64][65];
  const int kt = blockIdx.x * 64;
  const int nt = blockIdx.y * 64;
  const int e = blockIdx.z;
  const int tr = threadIdx.x >> 6;
  const int tc = threadIdx.x & 63;
  const float* wp = w + (size_t)e * HID * HID;
#pragma unroll
  for (int r = 0; r < 64; r += 4)
    tile[r + tr][tc] = wp[(size_t)(kt + r + tr) * HID + nt + tc];
  __syncthreads();
  unsigned short* wo = wt + (size_t)e * HID * HID;
  const int a = threadIdx.x & 31;   // k-pair index
  const int rg = threadIdx.x >> 5;  // row-in-group 0..7
#pragma unroll
  for (int c = 0; c < 64; c += 8) {
    const int n = c + rg;
    const unsigned lo = f2bf_rne(tile[2 * a][n]);
    const unsigned hi = f2bf_rne(tile[2 * a + 1][n]);
    *(unsigned int*)(wo + (size_t)(nt + n) * HID + kt + 2 * a) = lo | (hi << 16);
  }
}

// grouped GEMM: Y[row,n] = gate[row] * (X[tok[row],:] @ We[:,n]), bf16 out.
// 1-D swizzled grid: n0=(bx&7)*128 -> under round-robin XCD dispatch each XCD
// owns one n-strip (W strip L2-resident, expert-sorted table); under
// contiguous dispatch the 8 n-strips of one mblock are temporally adjacent.
__global__ __launch_bounds__(256, 4) void moe_ggemm_kernel(
    const unsigned short* __restrict__ Xb, const unsigned short* __restrict__ Wt,
    const unsigned int* __restrict__ table, const unsigned int* __restrict__ total,
    const unsigned int* __restrict__ tokmap, const float* __restrict__ gpos,
    unsigned short* __restrict__ Y) {
  __shared__ unsigned short As[128 * 32];
  __shared__ unsigned short Bs[128 * 32];
  __shared__ unsigned int Ts[128];
  __shared__ float Gs[128];

  const unsigned tot = *total;
  const unsigned bx = blockIdx.x;
  const unsigned slot = bx >> 3;
  if (slot >= tot) return;
  const int n0 = (bx & 7) * 128;
  const unsigned ent = table[slot];
  const int e = ent >> 24;
  const int row0 = ent & 0xFFFFFF;

  const int tid = threadIdx.x;
  const int wv = tid >> 6;
  const int lane = tid & 63;
  const int lm = lane & 15;
  const int quad = lane >> 4;
  const int woff_m = (wv & 1) * 64;
  const int woff_n = (wv >> 1) * 64;

  if (tid < 128) {
    Ts[tid] = tokmap[row0 + tid];
    Gs[tid] = gpos[row0 + tid];
  }
  __syncthreads();

  const int srow = wv * 32 + (lane >> 2);
  const int schunk = (lane & 3) * 16;
  const char* gA0 = (const char*)Xb + (size_t)Ts[srow] * (HID * 2) + schunk;
  const char* gA1 = (const char*)Xb + (size_t)Ts[srow + 16] * (HID * 2) + schunk;
  const char* gB0 = (const char*)Wt + (size_t)e * (HID * HID * 2) +
                    (size_t)(n0 + srow) * (HID * 2) + schunk;
  const char* gB1 = gB0 + 16 * HID * 2;
  char* const lA0 = (char*)As + (wv * 32) * 64;
  char* const lA1 = lA0 + 16 * 64;
  char* const lB0 = (char*)Bs + (wv * 32) * 64;
  char* const lB1 = lB0 + 16 * 64;

  f32x4 acc[4][4];
#pragma unroll
  for (int i = 0; i < 4; ++i)
#pragma unroll
    for (int j = 0; j < 4; ++j) acc[i][j] = (f32x4){0.f, 0.f, 0.f, 0.f};

  for (int ks = 0; ks < 32; ++ks) {
    __syncthreads();
    load_lds16(gA0, lA0);
    load_lds16(gA1, lA1);
    load_lds16(gB0, lB0);
    load_lds16(gB1, lB1);
    gA0 += 64; gA1 += 64; gB0 += 64; gB1 += 64;
    __syncthreads();

    bf16x8 a[4], b[4];
#pragma unroll
    for (int i = 0; i < 4; ++i)
      a[i] = *(const bf16x8*)((const char*)As +
                              (woff_m + 16 * i + lm) * 64 + quad * 16);
#pragma unroll
    for (int j = 0; j < 4; ++j)
      b[j] = *(const bf16x8*)((const char*)Bs +
                              (woff_n + 16 * j + lm) * 64 + quad * 16);
#pragma unroll
    for (int i = 0; i < 4; ++i)
#pragma unroll
      for (int j = 0; j < 4; ++j)
        acc[i][j] =
            __builtin_amdgcn_mfma_f32_16x16x32_bf16(a[i], b[j], acc[i][j], 0, 0, 0);
  }

#pragma unroll
  for (int i = 0; i < 4; ++i)
#pragma unroll
    for (int r = 0; r < 4; ++r) {
      const int row = woff_m + 16 * i + quad * 4 + r;
      const float g = Gs[row];
      unsigned short* yrow = Y + (size_t)(row0 + row) * HID + n0;
#pragma unroll
      for (int j = 0; j < 4; ++j)
        yrow[woff_n + 16 * j + lm] = (unsigned short)f2bf_rne(g * acc[i][j][r]);
    }
}

// reduce: out[t,:] = sum_k Y[inv[t,k],:] + eps[t].  2 tokens/block.
__global__ __launch_bounds__(256) void reduce_kernel(
    const unsigned short* __restrict__ Y, const unsigned int* __restrict__ inv,
    const float* __restrict__ epst, float* __restrict__ out) {
  const int sub = threadIdx.x >> 7;
  const int ct = threadIdx.x & 127;
  const int t = blockIdx.x * 2 + sub;
  const int c0 = ct * 8;

  float s[8];
  const float ep = epst[t];
#pragma unroll
  for (int i = 0; i < 8; ++i) s[i] = ep;

#pragma unroll
  for (int k = 0; k < TOPK; ++k) {
    const unsigned pos = inv[(size_t)t * TOPK + k];
    const uint4 v = *(const uint4*)(Y + (size_t)pos * HID + c0);
    s[0] += bfbits2f(v.x & 0xFFFFu);
    s[1] += bfbits2f(v.x >> 16);
    s[2] += bfbits2f(v.y & 0xFFFFu);
    s[3] += bfbits2f(v.y >> 16);
    s[4] += bfbits2f(v.z & 0xFFFFu);
    s[5] += bfbits2f(v.z >> 16);
    s[6] += bfbits2f(v.w & 0xFFFFu);
    s[7] += bfbits2f(v.w >> 16);
  }
  float* orow = out + (size_t)t * HID + c0;
  *(float4*)orow = (float4){s[0], s[1], s[2], s[3]};
  *(float4*)(orow + 4) = (float4){s[4], s[5], s[6], s[7]};
}

extern "C" void kernel_launch(void* const* d_in, const int* in_sizes, int n_in,
                              void* d_out, int out_size, void* d_ws, size_t ws_size,
                              hipStream_t stream) {
  const float* tokens = (const float*)d_in[0];  // [4,2048,1024] f32
  const float* rw = (const float*)d_in[1];      // [16,1024] f32
  const float* rb = (const float*)d_in[2];      // [16] f32
  const float* ew = (const float*)d_in[3];      // [16,1024,1024] f32
  float* out = (float*)d_out;                   // [4,2048,1024] f32

  char* ws = (char*)d_ws;
  const size_t OFF_XB = 0;                        // 16 MB
  const size_t OFF_WT = 16777216;                 // 32 MB
  const size_t OFF_Y = 50331648;                  // 100 MB (51200 x 1024 bf16)
  const size_t OFF_META = 155189248;
  const size_t M_TOKMAP = OFF_META + 0;           // 51200 u32
  const size_t M_GPOS = OFF_META + 204800;        // 51200 f32
  const size_t M_TOTAL = OFF_META + 409600;       // 1 u32 (pad 64)
  const size_t M_TABLE = OFF_META + 409664;       // 400 u32 (pad)
  const size_t M_INV = OFF_META + 411328;         // 49152 u32
  const size_t M_TOPK = OFF_META + 607936;        // 8192 u32
  const size_t M_G6 = OFF_META + 640704;          // 49152 f32
  const size_t M_EPST = OFF_META + 837312;        // 8192 f32

  unsigned short* Xb = (unsigned short*)(ws + OFF_XB);
  unsigned short* Wt = (unsigned short*)(ws + OFF_WT);
  unsigned short* Y = (unsigned short*)(ws + OFF_Y);
  unsigned int* tokmap = (unsigned int*)(ws + M_TOKMAP);
  float* gpos = (float*)(ws + M_GPOS);
  unsigned int* total = (unsigned int*)(ws + M_TOTAL);
  unsigned int* table = (unsigned int*)(ws + M_TABLE);
  unsigned int* inv = (unsigned int*)(ws + M_INV);
  unsigned int* topk = (unsigned int*)(ws + M_TOPK);
  float* g6 = (float*)(ws + M_G6);
  float* epst = (float*)(ws + M_EPST);

  router_sparse_kernel<<<dim3(NTOK / 4), dim3(256), 0, stream>>>(
      tokens, rw, rb, Xb, topk, g6, epst);
  cvt_wt_kernel<<<dim3(HID / 64, HID / 64, NE), dim3(256), 0, stream>>>(ew, Wt);
  sortassign_kernel<<<dim3(NE), dim3(256), 0, stream>>>(
      topk, g6, tokmap, gpos, inv, table, total);
  moe_ggemm_kernel<<<dim3(MAXBLK * 8), dim3(256), 0, stream>>>(
      Xb, Wt, table, total, tokmap, gpos, Y);
  reduce_kernel<<<dim3(NTOK / 2), dim3(256), 0, stream>>>(Y, inv, epst, out);
}